// Round 8
// baseline (924.824 us; speedup 1.0000x reference)
//
#include <hip/hip_runtime.h>

#define C_ 256
#define HW_ 65536
#define IMG_ (C_*HW_)

typedef __attribute__((ext_vector_type(4))) float f32x4;
typedef __attribute__((ext_vector_type(8))) short s16x8;
typedef unsigned long long ull;

__device__ __forceinline__ ushort f2bf(float f) {
  union { float f; unsigned u; } v; v.f = f;
  unsigned u = v.u;
  return (ushort)((u + 0x7fffu + ((u >> 16) & 1u)) >> 16);
}

__device__ __forceinline__ s16x8 ldfrag(const ushort* p) {
  s16x8 v;
  ((ull*)&v)[0] = *(const ull*)(p);
  ((ull*)&v)[1] = *(const ull*)(p + 4);
  return v;
}

__device__ __forceinline__ void st8(ushort* d, uint4 u) {
  *(ull*)(d)     = ((ull*)&u)[0];
  *(ull*)(d + 4) = ((ull*)&u)[1];
}

// ---------------- per-plane stats ----------------
__global__ void k_stats1(const float* __restrict__ x, float2* __restrict__ part) {
  int bid = blockIdx.x;                  // 1024 = (b,c) planes
  int tid = threadIdx.x;
  const f32x4* p = (const f32x4*)(x + (size_t)bid*65536);
  float s = 0.f, ss = 0.f;
  #pragma unroll 4
  for (int i = tid; i < 16384; i += 256) {
    f32x4 v = p[i];
    s  += v[0]+v[1]+v[2]+v[3];
    ss += v[0]*v[0]+v[1]*v[1]+v[2]*v[2]+v[3]*v[3];
  }
  __shared__ float sa[256], sb[256];
  sa[tid]=s; sb[tid]=ss; __syncthreads();
  for (int k=128;k>0;k>>=1){
    if (tid<k){ sa[tid]+=sa[tid+k]; sb[tid]+=sb[tid+k]; }
    __syncthreads();
  }
  if (tid==0) part[bid] = make_float2(sa[0], sb[0]);
}

// ---------------- fold GN stats into per-batch bf16 weights + emit stats ----------------
__global__ void k_fold(const float* __restrict__ wq, const float* __restrict__ bq,
                       const float* __restrict__ wk, const float* __restrict__ bk,
                       const float* __restrict__ wv, const float* __restrict__ bv,
                       const float* __restrict__ wo, const float* __restrict__ bo,
                       const float* __restrict__ gamma, const float* __restrict__ beta,
                       const float2* __restrict__ part,
                       ushort* __restrict__ wAll, ushort* __restrict__ woE,
                       float* __restrict__ biasAll, float2* __restrict__ statsOut) {
  int id = blockIdx.x, co = threadIdx.x;
  if (id == 12) {
    for (int c4 = 0; c4 < 64; ++c4) {
      ushort4 pk;
      pk.x = f2bf(wo[co*256 + c4*4 + 0]);
      pk.y = f2bf(wo[co*256 + c4*4 + 1]);
      pk.z = f2bf(wo[co*256 + c4*4 + 2]);
      pk.w = f2bf(wo[co*256 + c4*4 + 3]);
      *(ushort4*)&woE[co*256 + c4*4] = pk;
    }
    biasAll[3072 + co] = bo[co];
    return;
  }
  int m = id >> 2, b = id & 3;
  __shared__ float mean_s[32], rstd_s[32];
  __shared__ float aS[256], cS[256];
  if (co < 32) {
    float s = 0.f, ss = 0.f;
    for (int j = 0; j < 8; ++j) { float2 v = part[b*256 + co*8 + j]; s += v.x; ss += v.y; }
    float mean = s * (1.f/524288.f);
    float var  = ss * (1.f/524288.f) - mean*mean;
    mean_s[co] = mean; rstd_s[co] = rsqrtf(var + 1e-6f);
  }
  __syncthreads();
  if (m == 0 && co < 32) statsOut[b*32 + co] = make_float2(mean_s[co], rstd_s[co]);
  { int g2 = co >> 3; float a = rstd_s[g2]*gamma[co]; aS[co] = a; cS[co] = beta[co] - mean_s[g2]*a; }
  __syncthreads();
  const float* W  = m==0 ? wq : m==1 ? wk : wv;
  const float* bi = m==0 ? bq : m==1 ? bk : bv;
  float s = (m==0) ? 0.0625f : 1.0f;
  float acc = bi[co];
  ushort* dst = wAll + ((size_t)(m*4 + b)*256 + co)*256;
  for (int c4 = 0; c4 < 64; ++c4) {
    ushort4 pk; float wv_;
    wv_ = W[co*256 + c4*4 + 0]; acc += wv_*cS[c4*4+0]; pk.x = f2bf(wv_*aS[c4*4+0]*s);
    wv_ = W[co*256 + c4*4 + 1]; acc += wv_*cS[c4*4+1]; pk.y = f2bf(wv_*aS[c4*4+1]*s);
    wv_ = W[co*256 + c4*4 + 2]; acc += wv_*cS[c4*4+2]; pk.z = f2bf(wv_*aS[c4*4+2]*s);
    wv_ = W[co*256 + c4*4 + 3]; acc += wv_*cS[c4*4+3]; pk.w = f2bf(wv_*aS[c4*4+3]*s);
    *(ushort4*)&dst[c4*4] = pk;
  }
  biasAll[m*1024 + b*256 + co] = acc * s;
}

// ---------------- GN-normalize + bf16 + window transpose: x -> xnT[win][t][c] ----------------
__global__ __launch_bounds__(256) void k_xt(const float* __restrict__ x,
    const float2* __restrict__ stats, ushort* __restrict__ xnT) {
  int g = blockIdx.x;
  int win = (g & 7)*128 + (g >> 3);
  int b = win >> 8, wy = (win >> 4) & 15, wx = win & 15;
  int tid = threadIdx.x;
  const float* xw = x + (size_t)b*IMG_ + wy*16*256 + wx*16;
  ushort* outp = xnT + (size_t)win*65536;
  __shared__ __align__(16) ushort tile[64*260];
  for (int cc = 0; cc < 4; ++cc) {
    int cbase = cc*64;
    __syncthreads();
    #pragma unroll
    for (int r = 0; r < 16; ++r) {
      int task = tid + 256*r;
      int cl = task >> 6, t4 = task & 63;
      int t = t4*4;
      int ci = cbase + cl;
      f32x4 v = *(const f32x4*)(xw + (size_t)ci*HW_ + (t >> 4)*256 + (t & 15));
      float2 st = stats[b*32 + (ci >> 3)];
      unsigned p0 = (unsigned)f2bf((v[0]-st.x)*st.y) | ((unsigned)f2bf((v[1]-st.x)*st.y) << 16);
      unsigned p1 = (unsigned)f2bf((v[2]-st.x)*st.y) | ((unsigned)f2bf((v[3]-st.x)*st.y) << 16);
      ull pk = (ull)p0 | ((ull)p1 << 32);
      *(ull*)&tile[cl*260 + t] = pk;
    }
    __syncthreads();
    int pr = tid & 127, sub = tid >> 7;
    int t0 = 2*pr;
    const unsigned* tw = (const unsigned*)tile;
    unsigned lo[16], hi[16];
    #pragma unroll
    for (int k = 0; k < 16; ++k) {
      unsigned a  = tw[(sub*32 + 2*k    )*130 + pr];
      unsigned b2 = tw[(sub*32 + 2*k + 1)*130 + pr];
      lo[k] = (a & 0xffffu) | (b2 << 16);
      hi[k] = (a >> 16) | (b2 & 0xffff0000u);
    }
    ushort* o0 = outp + (size_t)t0*256 + cbase + sub*32;
    ushort* o1 = o0 + 256;
    *(uint4*)(o0)      = *(uint4*)&lo[0];
    *(uint4*)(o0 + 8)  = *(uint4*)&lo[4];
    *(uint4*)(o0 + 16) = *(uint4*)&lo[8];
    *(uint4*)(o0 + 24) = *(uint4*)&lo[12];
    *(uint4*)(o1)      = *(uint4*)&hi[0];
    *(uint4*)(o1 + 8)  = *(uint4*)&hi[4];
    *(uint4*)(o1 + 16) = *(uint4*)&hi[8];
    *(uint4*)(o1 + 24) = *(uint4*)&hi[12];
  }
}

// ---------------- projection GEMM: 128x128 blocks, 64x64/wave (occupancy 3/CU) ----------------
// mat 0/1 -> Qt/Kt[win][t][c]; mat 2 -> V[win][c][t]
// phase 0: Q,V (8/win); phase 1: K (4/win, in place over xnT); phase 2: all (12/win)
__global__ __launch_bounds__(256, 3) void k_proj(const ushort* __restrict__ xnT,
    const ushort* __restrict__ wAll, const float* __restrict__ biasAll,
    ushort* __restrict__ Qt, ushort* __restrict__ Kt, ushort* __restrict__ V,
    int phase) {
  int g = blockIdx.x;
  int xcd = g & 7, i = g >> 3;
  int win, mat, q;
  if (phase == 2)      { int wq_ = i/12; win = xcd*128 + wq_; int r = i - wq_*12; mat = r >> 2; q = r & 3; }
  else if (phase == 0) { win = xcd*128 + (i >> 3); int r = i & 7; mat = (r < 4) ? 0 : 2; q = r & 3; }
  else                 { win = xcd*128 + (i >> 2); mat = 1; q = i & 3; }
  int t0 = (q >> 1)*128, c0 = (q & 1)*128;
  int b = win >> 8;
  int tid = threadIdx.x, l = tid & 63, wid = tid >> 6, h = l >> 4, lr = l & 15;
  int wr = wid >> 1, wc = wid & 1;

  // dbuf: buffer k at k*9216 (ushort units): X[128][36] @+0, W[128][36] @+4608
  __shared__ __align__(16) ushort smem[18432];

  const ushort* xsrc = xnT + (size_t)win*65536 + (size_t)t0*256;
  const ushort* wsrc = wAll + (size_t)(mat*4 + b)*65536 + (size_t)c0*256;

  int srow = tid >> 1, shh = (tid & 1)*16;
  const ushort* xg = xsrc + (size_t)srow*256 + shh;
  const ushort* wg = wsrc + (size_t)srow*256 + shh;

  f32x4 acc[4][4];
  #pragma unroll
  for (int a = 0; a < 4; ++a)
    #pragma unroll
    for (int n = 0; n < 4; ++n) acc[a][n] = (f32x4){0.f,0.f,0.f,0.f};

  int aoff = (mat < 2) ? 0 : 4608;     // A rows: t (xlds) or co (wlds)
  int boff = (mat < 2) ? 4608 : 0;

  uint4 rx0, rx1, rw0, rw1;
  rx0 = *(const uint4*)(xg);     rx1 = *(const uint4*)(xg + 8);
  rw0 = *(const uint4*)(wg);     rw1 = *(const uint4*)(wg + 8);
  {
    ushort* xd = smem + srow*36 + shh;
    st8(xd, rx0); st8(xd + 8, rx1);
    ushort* wd = smem + 4608 + srow*36 + shh;
    st8(wd, rw0); st8(wd + 8, rw1);
  }
  __syncthreads();

  int cur = 0;
  for (int ck = 0; ck < 8; ++ck) {
    if (ck < 7) {
      const ushort* xp = xg + (ck + 1)*32;
      const ushort* wp = wg + (ck + 1)*32;
      rx0 = *(const uint4*)(xp);   rx1 = *(const uint4*)(xp + 8);
      rw0 = *(const uint4*)(wp);   rw1 = *(const uint4*)(wp + 8);
    }
    const ushort* ab = smem + cur*9216 + aoff;
    const ushort* bb = smem + cur*9216 + boff;
    s16x8 af[4], bf[4];
    #pragma unroll
    for (int ms = 0; ms < 4; ++ms)
      af[ms] = ldfrag(ab + (size_t)(wr*64 + ms*16 + lr)*36 + h*8);
    #pragma unroll
    for (int ns = 0; ns < 4; ++ns)
      bf[ns] = ldfrag(bb + (size_t)(wc*64 + ns*16 + lr)*36 + h*8);
    #pragma unroll
    for (int ms = 0; ms < 4; ++ms)
      #pragma unroll
      for (int ns = 0; ns < 4; ++ns)
        acc[ms][ns] = __builtin_amdgcn_mfma_f32_16x16x32_bf16(af[ms], bf[ns], acc[ms][ns], 0,0,0);
    if (ck < 7) {
      ushort* xd = smem + (cur^1)*9216 + srow*36 + shh;
      st8(xd, rx0); st8(xd + 8, rx1);
      ushort* wd = smem + (cur^1)*9216 + 4608 + srow*36 + shh;
      st8(wd, rw0); st8(wd + 8, rw1);
    }
    __syncthreads();
    cur ^= 1;
  }

  // ---- epilogue: 2 slab passes [128][68] over B-dim 64-halves; wide 16B stores ----
  ushort* dst = (mat == 0) ? Qt + (size_t)win*65536
              : (mat == 1) ? Kt + (size_t)win*65536
                           : V  + (size_t)win*65536;
  int row0 = (mat < 2) ? t0 : c0;
  int col0 = (mat < 2) ? c0 : t0;

  float bc[4]; f32x4 br[4];
  if (mat < 2) {
    #pragma unroll
    for (int ns = 0; ns < 4; ++ns)
      bc[ns] = biasAll[mat*1024 + b*256 + c0 + wc*64 + ns*16 + lr];
  } else {
    #pragma unroll
    for (int ms = 0; ms < 4; ++ms)
      br[ms] = *(const f32x4*)&biasAll[2048 + b*256 + c0 + wr*64 + ms*16 + 4*h];
  }

  #pragma unroll
  for (int sl = 0; sl < 2; ++sl) {
    if (wc == sl) {
      #pragma unroll
      for (int ms = 0; ms < 4; ++ms)
        #pragma unroll
        for (int ns = 0; ns < 4; ++ns)
          #pragma unroll
          for (int j = 0; j < 4; ++j) {
            int row = wr*64 + ms*16 + 4*h + j;
            float v = acc[ms][ns][j] + ((mat < 2) ? bc[ns] : br[ms][j]);
            smem[row*68 + ns*16 + lr] = f2bf(v);
          }
    }
    __syncthreads();
    #pragma unroll
    for (int p = 0; p < 4; ++p) {
      int rr = p*32 + (tid >> 3), seg = tid & 7;
      const ushort* sp = &smem[rr*68 + seg*8];
      uint4 v;
      ((ull*)&v)[0] = *(const ull*)sp;
      ((ull*)&v)[1] = *(const ull*)(sp + 4);
      *(uint4*)(dst + (size_t)(row0 + rr)*256 + col0 + sl*64 + seg*8) = v;
    }
    if (sl == 0) __syncthreads();
  }
}

// ---------------- windowed attention: q-split waves, Q-in-regs, 64-key tiles ----------------
__global__ __launch_bounds__(256, 2) void k_attn(const ushort* __restrict__ Qt,
    const ushort* __restrict__ Kt, const ushort* __restrict__ V,
    ushort* __restrict__ AO) {
  int g = blockIdx.x;
  int i = g >> 3;
  int w = (g & 7)*128 + (i >> 2), qt = i & 3;
  int q0 = qt * 64;
  int tid = threadIdx.x, l = tid & 63, wid = tid >> 6, h = l >> 4, lr = l & 15;
  __shared__ __align__(16) ushort KV[17408];
  __shared__ __align__(16) ushort Ps[4][1088];   // per-wave P-subtile [16 q][68]
  const ushort* qbase = Qt + (size_t)w*65536;
  const ushort* kbase = Kt + (size_t)w*65536;
  const ushort* vbase = V  + (size_t)w*65536;

  s16x8 qf[8];
  {
    const ushort* qp = qbase + (size_t)(q0 + wid*16 + lr)*256 + h*8;
    #pragma unroll
    for (int dk = 0; dk < 8; ++dk) {
      uint4 u = *(const uint4*)(qp + dk*32);
      qf[dk] = *(s16x8*)&u;
    }
  }

  int krow = tid >> 2, kseg = (tid & 3)*64;
  const ushort* kg = kbase + (size_t)krow*256 + kseg;
  ushort* kd = &KV[krow*260 + kseg];
  const ushort* vg = vbase + (size_t)tid*256;
  ushort* vd = &KV[tid*68];

  uint4 rv[8];
  #pragma unroll
  for (int u = 0; u < 8; ++u) rv[u] = *(const uint4*)(kg + u*8);
  #pragma unroll
  for (int u = 0; u < 8; ++u) st8(kd + u*8, rv[u]);
  __syncthreads();

  f32x4 accS[16];
  #pragma unroll
  for (int n = 0; n < 16; ++n) accS[n] = (f32x4){0.f,0.f,0.f,0.f};

  #pragma unroll
  for (int kt = 0; kt < 4; ++kt) {
    if (kt < 3) {
      const ushort* kp = kg + (size_t)(kt + 1)*64*256;
      #pragma unroll
      for (int u = 0; u < 8; ++u) rv[u] = *(const uint4*)(kp + u*8);
    } else {
      #pragma unroll
      for (int u = 0; u < 8; ++u) rv[u] = *(const uint4*)(vg + u*8);
    }
    #pragma unroll
    for (int ns = 0; ns < 4; ++ns) {
      #pragma unroll
      for (int dstep = 0; dstep < 8; ++dstep) {
        s16x8 kf = ldfrag(&KV[(ns*16 + lr)*260 + dstep*32 + h*8]);
        accS[kt*4 + ns] = __builtin_amdgcn_mfma_f32_16x16x32_bf16(qf[dstep], kf, accS[kt*4 + ns], 0,0,0);
      }
    }
    __syncthreads();
    if (kt < 3) {
      #pragma unroll
      for (int u = 0; u < 8; ++u) st8(kd + u*8, rv[u]);
    } else {
      #pragma unroll
      for (int u = 0; u < 8; ++u) st8(vd + u*8, rv[u]);
    }
    __syncthreads();
  }

  #pragma unroll
  for (int j = 0; j < 4; ++j) {
    float m_ = accS[0][j];
    #pragma unroll
    for (int n = 1; n < 16; ++n) m_ = fmaxf(m_, accS[n][j]);
    #pragma unroll
    for (int msk = 1; msk < 16; msk <<= 1) m_ = fmaxf(m_, __shfl_xor(m_, msk));
    float s_ = 0.f;
    #pragma unroll
    for (int n = 0; n < 16; ++n) {
      float p = __expf(accS[n][j] - m_);
      accS[n][j] = p;
      s_ += p;
    }
    #pragma unroll
    for (int msk = 1; msk < 16; msk <<= 1) s_ += __shfl_xor(s_, msk);
    float ri = 1.f / s_;
    #pragma unroll
    for (int n = 0; n < 16; ++n) accS[n][j] *= ri;
  }

  // PV: Ps write -> __syncthreads() -> ldfrag is REQUIRED (round-6 NaN lesson)
  f32x4 accO[16];
  #pragma unroll
  for (int n = 0; n < 16; ++n) accO[n] = (f32x4){0.f,0.f,0.f,0.f};

  #pragma unroll
  for (int kt = 0; kt < 4; ++kt) {
    if (kt < 3) {
      const ushort* vp = vg + (kt + 1)*64;
      #pragma unroll
      for (int u = 0; u < 8; ++u) rv[u] = *(const uint4*)(vp + u*8);
    }
    #pragma unroll
    for (int ns = 0; ns < 4; ++ns)
      #pragma unroll
      for (int j = 0; j < 4; ++j)
        Ps[wid][(4*h + j)*68 + ns*16 + lr] = f2bf(accS[kt*4 + ns][j]);
    __syncthreads();
    #pragma unroll
    for (int ks = 0; ks < 2; ++ks) {
      s16x8 pf = ldfrag(&Ps[wid][lr*68 + ks*32 + h*8]);
      #pragma unroll
      for (int ns = 0; ns < 16; ++ns) {
        s16x8 vf = ldfrag(&KV[(ns*16 + lr)*68 + ks*32 + h*8]);
        accO[ns] = __builtin_amdgcn_mfma_f32_16x16x32_bf16(pf, vf, accO[ns], 0,0,0);
      }
    }
    __syncthreads();
    if (kt < 3) {
      #pragma unroll
      for (int u = 0; u < 8; ++u) st8(vd + u*8, rv[u]);
      __syncthreads();
    }
  }

  #pragma unroll
  for (int ns = 0; ns < 16; ++ns)
    #pragma unroll
    for (int j = 0; j < 4; ++j)
      KV[(wid*16 + 4*h + j)*260 + ns*16 + lr] = f2bf(accO[ns][j]);
  __syncthreads();
  ushort* aob = AO + (size_t)w*65536;
  #pragma unroll
  for (int it = 0; it < 8; ++it) {
    int task = tid + 256*it;
    int r = task >> 5, seg = task & 31;
    const ushort* sp = &KV[r*260 + seg*8];
    uint4 v;
    ((ull*)&v)[0] = *(const ull*)sp;
    ((ull*)&v)[1] = *(const ull*)(sp + 4);
    *(uint4*)(aob + (size_t)(q0 + r)*256 + seg*8) = v;
  }
}

// ---------------- output projection + residual: 128x128 blocks, 64x64/wave ----------------
__global__ __launch_bounds__(256, 3) void k_oproj(const float* __restrict__ x,
    const ushort* __restrict__ AO, const ushort* __restrict__ woE,
    const float* __restrict__ biasAll, float* __restrict__ y) {
  int g = blockIdx.x;
  int i = g >> 3;
  int w = (g & 7)*128 + (i >> 2);
  int q = i & 3;
  int o0 = (q >> 1)*128, t0 = (q & 1)*128;
  int b = w >> 8, wy = (w >> 4) & 15, wx = w & 15;
  int tid = threadIdx.x, l = tid & 63, wid = tid >> 6, h = l >> 4, lr = l & 15;
  int wr = wid >> 1, wc = wid & 1;

  // dbuf: buffer k at k*9216: W[128][36] @+0 (A rows = o), AO[128][36] @+4608 (B rows = t)
  __shared__ __align__(16) ushort smem[18432];

  const ushort* abase = AO + (size_t)w*65536 + (size_t)t0*256;
  const ushort* wbase = woE + (size_t)o0*256;

  int srow = tid >> 1, shh = (tid & 1)*16;
  const ushort* ag = abase + (size_t)srow*256 + shh;
  const ushort* wg = wbase + (size_t)srow*256 + shh;

  f32x4 acc[4][4];
  #pragma unroll
  for (int a = 0; a < 4; ++a)
    #pragma unroll
    for (int n = 0; n < 4; ++n) acc[a][n] = (f32x4){0.f,0.f,0.f,0.f};

  uint4 rw0, rw1, ra0, ra1;
  rw0 = *(const uint4*)(wg);     rw1 = *(const uint4*)(wg + 8);
  ra0 = *(const uint4*)(ag);     ra1 = *(const uint4*)(ag + 8);
  {
    ushort* wd = smem + srow*36 + shh;
    st8(wd, rw0); st8(wd + 8, rw1);
    ushort* ad = smem + 4608 + srow*36 + shh;
    st8(ad, ra0); st8(ad + 8, ra1);
  }
  __syncthreads();

  int cur = 0;
  for (int ck = 0; ck < 8; ++ck) {
    if (ck < 7) {
      const ushort* wp = wg + (ck + 1)*32;
      const ushort* ap = ag + (ck + 1)*32;
      rw0 = *(const uint4*)(wp);   rw1 = *(const uint4*)(wp + 8);
      ra0 = *(const uint4*)(ap);   ra1 = *(const uint4*)(ap + 8);
    }
    const ushort* wb = smem + cur*9216;
    const ushort* ab = smem + cur*9216 + 4608;
    s16x8 af[4], bf[4];
    #pragma unroll
    for (int ms = 0; ms < 4; ++ms)
      af[ms] = ldfrag(wb + (size_t)(wr*64 + ms*16 + lr)*36 + h*8);
    #pragma unroll
    for (int ns = 0; ns < 4; ++ns)
      bf[ns] = ldfrag(ab + (size_t)(wc*64 + ns*16 + lr)*36 + h*8);
    #pragma unroll
    for (int ms = 0; ms < 4; ++ms)
      #pragma unroll
      for (int ns = 0; ns < 4; ++ns)
        acc[ms][ns] = __builtin_amdgcn_mfma_f32_16x16x32_bf16(af[ms], bf[ns], acc[ms][ns], 0,0,0);
    if (ck < 7) {
      ushort* wd = smem + (cur^1)*9216 + srow*36 + shh;
      st8(wd, rw0); st8(wd + 8, rw1);
      ushort* ad = smem + (cur^1)*9216 + 4608 + srow*36 + shh;
      st8(ad, ra0); st8(ad + 8, ra1);
    }
    __syncthreads();
    cur ^= 1;
  }

  const float* xw = x + (size_t)b*IMG_ + wy*16*256 + wx*16;
  float* yw = y + (size_t)b*IMG_ + wy*16*256 + wx*16;
  #pragma unroll
  for (int ms = 0; ms < 4; ++ms) {
    f32x4 b4 = *(const f32x4*)&biasAll[3072 + o0 + wr*64 + ms*16 + 4*h];
    #pragma unroll
    for (int j = 0; j < 4; ++j) {
      int o = o0 + wr*64 + ms*16 + 4*h + j;
      #pragma unroll
      for (int ns = 0; ns < 4; ++ns) {
        int t = t0 + wc*64 + ns*16 + lr;
        size_t off = (size_t)o*HW_ + (t >> 4)*256 + (t & 15);
        yw[off] = xw[off] + acc[ms][ns][j] + b4[j];
      }
    }
  }
}

extern "C" void kernel_launch(void* const* d_in, const int* in_sizes, int n_in,
                              void* d_out, int out_size, void* d_ws, size_t ws_size,
                              hipStream_t stream) {
  const float* x     = (const float*)d_in[0];
  const float* gamma = (const float*)d_in[1];
  const float* beta  = (const float*)d_in[2];
  const float* wq = (const float*)d_in[3];
  const float* bq = (const float*)d_in[4];
  const float* wk = (const float*)d_in[5];
  const float* bk = (const float*)d_in[6];
  const float* wv = (const float*)d_in[7];
  const float* bv = (const float*)d_in[8];
  const float* wo = (const float*)d_in[9];
  const float* bo = (const float*)d_in[10];
  float* y = (float*)d_out;
  char* ws = (char*)d_ws;

  float2* part    = (float2*)ws;                        // 8 KB
  float*  biasAll = (float*)(ws + 8192);                // 13.3 KB
  float2* stats   = (float2*)(ws + 24576);              // 1 KB
  ushort* wAll    = (ushort*)(ws + 32768);              // 1.5 MB
  ushort* woE     = (ushort*)(ws + 32768 + 1572864);    // 128 KB
  ushort* Qt      = (ushort*)(ws + 2097152);            // 134 MB (also AO)
  ushort* xnT = (ushort*)d_out;
  ushort* V   = (ushort*)d_out + (size_t)67108864;

  k_stats1<<<1024, 256, 0, stream>>>(x, part);
  k_fold<<<13, 256, 0, stream>>>(wq,bq,wk,bk,wv,bv,wo,bo,gamma,beta,part,wAll,woE,biasAll,stats);
  k_xt<<<1024, 256, 0, stream>>>(x, stats, xnT);

  const size_t KT_SEP_NEED = 2097152ull + 2ull*134217728ull;
  if (ws_size >= KT_SEP_NEED) {
    ushort* Kt2 = (ushort*)(ws + 2097152 + 134217728);
    k_proj<<<12288, 256, 0, stream>>>(xnT, wAll, biasAll, Qt, Kt2, V, 2);
    k_attn<<<4096, 256, 0, stream>>>(Qt, Kt2, V, Qt /*AO alias: disjoint rows*/);
  } else {
    ushort* Kt = (ushort*)d_out;   // in place over xnT
    k_proj<<<8192, 256, 0, stream>>>(xnT, wAll, biasAll, Qt, Kt, V, 0);  // Q, V
    k_proj<<<4096, 256, 0, stream>>>(xnT, wAll, biasAll, Qt, Kt, V, 1);  // K (in place)
    k_attn<<<4096, 256, 0, stream>>>(Qt, Kt, V, Qt /*AO alias: disjoint rows*/);
  }
  k_oproj<<<4096, 256, 0, stream>>>(x, Qt /*AO*/, woE, biasAll, y);
}